// Round 1
// baseline (2075.658 us; speedup 1.0000x reference)
//
#include <hip/hip_runtime.h>
#include <math.h>

#define NN 50000
#define EE 600000
#define IND 128
#define HIDD 64
#define NH 4
#define EDD 16
#define OUTD 2
#define C1 256  /* NH*HIDD */

__device__ __forceinline__ float lrelu(float v){ return v > 0.f ? v : 0.2f*v; }
// order-preserving float->uint key for atomicMax-based segment max
__device__ __forceinline__ unsigned fkey(float f){
    unsigned u = __float_as_uint(f);
    return (u & 0x80000000u) ? ~u : (u | 0x80000000u);
}
__device__ __forceinline__ float fdec(unsigned k){
    unsigned u = (k & 0x80000000u) ? (k & 0x7FFFFFFFu) : ~k;
    return __uint_as_float(u);
}

// ---------------- layer 1 node linear: xl1 = x@W1l+b1l, xr1 = x@W1r+b1r ----
__global__ __launch_bounds__(256) void k_lin1(
    const float* __restrict__ x, const float* __restrict__ Wl, const float* __restrict__ bl,
    const float* __restrict__ Wr, const float* __restrict__ br,
    float* __restrict__ xl, float* __restrict__ xr)
{
    __shared__ float As[16 * IND];   // 16 rows x 128, broadcast reads -> no padding needed
    int t = threadIdx.x;
    int row0 = blockIdx.x * 16;
#pragma unroll
    for (int j = 0; j < 8; ++j) {
        int idx = t + j * 256;
        int r = idx >> 7, c = idx & 127;
        As[idx] = (row0 + r < NN) ? x[(size_t)(row0 + r) * IND + c] : 0.f;
    }
    __syncthreads();
    float accl[16], accr[16];
    float bL = bl[t], bR = br[t];
#pragma unroll
    for (int i = 0; i < 16; ++i) { accl[i] = bL; accr[i] = bR; }
    for (int k = 0; k < IND; ++k) {
        float wl = Wl[k * C1 + t];
        float wr = Wr[k * C1 + t];
#pragma unroll
        for (int i = 0; i < 16; ++i) {
            float a = As[i * IND + k];
            accl[i] = fmaf(a, wl, accl[i]);
            accr[i] = fmaf(a, wr, accr[i]);
        }
    }
#pragma unroll
    for (int i = 0; i < 16; ++i) {
        int r = row0 + i;
        if (r < NN) {
            xl[(size_t)r * C1 + t] = accl[i];
            xr[(size_t)r * C1 + t] = accr[i];
        }
    }
}

// ---------------- layer 1 edge logits + segment max -------------------------
__global__ __launch_bounds__(256) void k_elog1(
    const int* __restrict__ src, const int* __restrict__ dst,
    const float* __restrict__ ea, const float* __restrict__ We, const float* __restrict__ be,
    const float* __restrict__ att, const float* __restrict__ xl, const float* __restrict__ xr,
    float* __restrict__ logits, unsigned* __restrict__ amax)
{
    __shared__ float sW[EDD * C1];  // 16KB
    __shared__ float sb[C1];
    __shared__ float sa[C1];
    int t = threadIdx.x;
#pragma unroll
    for (int j = 0; j < EDD; ++j) sW[t + j * 256] = We[t + j * 256];
    sb[t] = be[t];
    sa[t] = att[t];
    __syncthreads();
    int w = t >> 6, lane = t & 63;
    for (int e = blockIdx.x * 4 + w; e < EE; e += gridDim.x * 4) {
        int s = src[e], d = dst[e];
        float eav[EDD];
#pragma unroll
        for (int k = 0; k < EDD; ++k) eav[k] = ea[(size_t)e * EDD + k];
        float lg[NH];
#pragma unroll
        for (int h = 0; h < NH; ++h) {
            int c = h * 64 + lane;
            float xe = sb[c];
#pragma unroll
            for (int k = 0; k < EDD; ++k) xe = fmaf(eav[k], sW[k * C1 + c], xe);
            float m = xl[(size_t)s * C1 + c] + xr[(size_t)d * C1 + c] + xe;
            m = lrelu(m);
            float p = m * sa[c];
#pragma unroll
            for (int off = 32; off > 0; off >>= 1) p += __shfl_down(p, off, 64);
            lg[h] = p;
        }
        if (lane == 0) {
#pragma unroll
            for (int h = 0; h < NH; ++h) {
                logits[(size_t)e * NH + h] = lg[h];
                atomicMax(&amax[d * NH + h], fkey(lg[h]));
            }
        }
    }
}

// ---------------- layer 1 exp + segment sum ---------------------------------
__global__ void k_exp1(const int* __restrict__ dst, float* __restrict__ logits,
                       const unsigned* __restrict__ amax, float* __restrict__ denom)
{
    int stride = gridDim.x * blockDim.x;
    for (int i = blockIdx.x * blockDim.x + threadIdx.x; i < EE * NH; i += stride) {
        int e = i >> 2, h = i & 3;
        int d = dst[e];
        float mx = fdec(amax[d * NH + h]);
        float ex = __expf(logits[i] - mx);
        logits[i] = ex;
        atomicAdd(&denom[d * NH + h], ex);
    }
}

// ---------------- layer 1 aggregation (atomic scatter) ----------------------
__global__ __launch_bounds__(256) void k_agg1(
    const int* __restrict__ src, const int* __restrict__ dst,
    const float* __restrict__ exv, const float* __restrict__ denom,
    const float* __restrict__ xl, float* __restrict__ h1)
{
    int t = threadIdx.x; int w = t >> 6, lane = t & 63;
    for (int e = blockIdx.x * 4 + w; e < EE; e += gridDim.x * 4) {
        int s = src[e], d = dst[e];
        float al[NH];
#pragma unroll
        for (int h = 0; h < NH; ++h) al[h] = exv[(size_t)e * NH + h] / denom[d * NH + h];
#pragma unroll
        for (int h = 0; h < NH; ++h) {
            int c = h * 64 + lane;
            atomicAdd(&h1[(size_t)d * C1 + c], al[h] * xl[(size_t)s * C1 + c]);
        }
    }
}

// ---------------- layer 2 node linear (fuses bias1+relu on load) ------------
__global__ __launch_bounds__(256) void k_lin2(
    const float* __restrict__ h1acc, const float* __restrict__ bias1,
    const float* __restrict__ Wl, const float* __restrict__ bl,
    const float* __restrict__ Wr, const float* __restrict__ br,
    float* __restrict__ xl2, float* __restrict__ xr2)
{
    __shared__ float As[16 * 257];  // +1 pad: 4 row-groups read 4 distinct rows at same k
    int t = threadIdx.x;
    int row0 = blockIdx.x * 16;
    float b1 = bias1[t];
#pragma unroll
    for (int j = 0; j < 16; ++j) {
        int r = j, c = t;
        float v = (row0 + r < NN) ? h1acc[(size_t)(row0 + r) * C1 + c] : 0.f;
        v = v + b1;
        As[r * 257 + c] = v > 0.f ? v : 0.f;
    }
    __syncthreads();
    int col = t & 63, g = t >> 6;
    float accl[4], accr[4];
    float bL = bl[col], bR = br[col];
#pragma unroll
    for (int i = 0; i < 4; ++i) { accl[i] = bL; accr[i] = bR; }
    for (int k = 0; k < C1; ++k) {
        float wl = Wl[k * HIDD + col];
        float wr = Wr[k * HIDD + col];
#pragma unroll
        for (int i = 0; i < 4; ++i) {
            float a = As[(g * 4 + i) * 257 + k];
            accl[i] = fmaf(a, wl, accl[i]);
            accr[i] = fmaf(a, wr, accr[i]);
        }
    }
#pragma unroll
    for (int i = 0; i < 4; ++i) {
        int r = row0 + g * 4 + i;
        if (r < NN) {
            xl2[(size_t)r * HIDD + col] = accl[i];
            xr2[(size_t)r * HIDD + col] = accr[i];
        }
    }
}

// ---------------- layer 2 edge logits + segment max -------------------------
__global__ __launch_bounds__(256) void k_elog2(
    const int* __restrict__ src, const int* __restrict__ dst,
    const float* __restrict__ ea, const float* __restrict__ We, const float* __restrict__ be,
    const float* __restrict__ att, const float* __restrict__ xl, const float* __restrict__ xr,
    float* __restrict__ logits, unsigned* __restrict__ amax)
{
    __shared__ float sW[EDD * HIDD];
    __shared__ float sb[HIDD];
    __shared__ float sa[HIDD];
    int t = threadIdx.x;
#pragma unroll
    for (int j = 0; j < 4; ++j) sW[t + j * 256] = We[t + j * 256];
    if (t < HIDD) { sb[t] = be[t]; sa[t] = att[t]; }
    __syncthreads();
    int w = t >> 6, lane = t & 63;
    for (int e = blockIdx.x * 4 + w; e < EE; e += gridDim.x * 4) {
        int s = src[e], d = dst[e];
        float xe = sb[lane];
#pragma unroll
        for (int k = 0; k < EDD; ++k) xe = fmaf(ea[(size_t)e * EDD + k], sW[k * HIDD + lane], xe);
        float m = xl[(size_t)s * HIDD + lane] + xr[(size_t)d * HIDD + lane] + xe;
        m = lrelu(m);
        float p = m * sa[lane];
#pragma unroll
        for (int off = 32; off > 0; off >>= 1) p += __shfl_down(p, off, 64);
        if (lane == 0) { logits[e] = p; atomicMax(&amax[d], fkey(p)); }
    }
}

// ---------------- layer 2 exp + segment sum ---------------------------------
__global__ void k_exp2(const int* __restrict__ dst, float* __restrict__ logits,
                       const unsigned* __restrict__ amax, float* __restrict__ denom)
{
    int stride = gridDim.x * blockDim.x;
    for (int e = blockIdx.x * blockDim.x + threadIdx.x; e < EE; e += stride) {
        int d = dst[e];
        float ex = __expf(logits[e] - fdec(amax[d]));
        logits[e] = ex;
        atomicAdd(&denom[d], ex);
    }
}

// ---------------- layer 2 aggregation ---------------------------------------
__global__ __launch_bounds__(256) void k_agg2(
    const int* __restrict__ src, const int* __restrict__ dst,
    const float* __restrict__ exv, const float* __restrict__ denom,
    const float* __restrict__ xl2, float* __restrict__ h2)
{
    int t = threadIdx.x; int w = t >> 6, lane = t & 63;
    for (int e = blockIdx.x * 4 + w; e < EE; e += gridDim.x * 4) {
        int s = src[e], d = dst[e];
        float al = exv[e] / denom[d];
        atomicAdd(&h2[(size_t)d * HIDD + lane], al * xl2[(size_t)s * HIDD + lane]);
    }
}

// ---------------- finalize h2 = relu(h2 + bias2) ----------------------------
__global__ void k_fin2(float* __restrict__ h2, const float* __restrict__ bias2)
{
    int stride = gridDim.x * blockDim.x;
    for (int i = blockIdx.x * blockDim.x + threadIdx.x; i < NN * HIDD; i += stride) {
        float v = h2[i] + bias2[i & 63];
        h2[i] = v > 0.f ? v : 0.f;
    }
}

// ---------------- edge MLP --------------------------------------------------
__global__ __launch_bounds__(256) void k_mlp(
    const int* __restrict__ src, const int* __restrict__ dst,
    const float* __restrict__ h2, const float* __restrict__ ea,
    const float* __restrict__ Wm1, const float* __restrict__ bm1,
    const float* __restrict__ Wm2, const float* __restrict__ bm2,
    float* __restrict__ out)
{
    __shared__ float sW1[144 * 64];   // 36.9 KB
    __shared__ float sEf[4][160];     // per-wave edge feature (64+64+16, padded)
    __shared__ float sW2[128];
    __shared__ float sb1[64];
    int t = threadIdx.x;
#pragma unroll
    for (int j = 0; j < 36; ++j) sW1[t + j * 256] = Wm1[t + j * 256];
    if (t < 128) sW2[t] = Wm2[t];
    if (t < 64)  sb1[t] = bm1[t];
    __syncthreads();
    float b20 = bm2[0], b21 = bm2[1];
    int w = t >> 6, lane = t & 63;
    for (int base = blockIdx.x * 4; base < EE; base += gridDim.x * 4) {
        int e = base + w;
        bool act = e < EE;
        if (act) {
            int s = src[e], d = dst[e];
            sEf[w][lane]      = h2[(size_t)s * HIDD + lane];
            sEf[w][64 + lane] = h2[(size_t)d * HIDD + lane];
            if (lane < EDD) sEf[w][128 + lane] = ea[(size_t)e * EDD + lane];
        }
        __syncthreads();   // also orders intra-wave LDS write->read
        float o0 = 0.f, o1 = 0.f;
        if (act) {
            float hl = sb1[lane];
#pragma unroll 16
            for (int k = 0; k < 144; ++k) hl = fmaf(sEf[w][k], sW1[k * 64 + lane], hl);
            hl = hl > 0.f ? hl : 0.f;
            o0 = hl * sW2[lane * 2];
            o1 = hl * sW2[lane * 2 + 1];
        }
#pragma unroll
        for (int off = 32; off > 0; off >>= 1) {
            o0 += __shfl_down(o0, off, 64);
            o1 += __shfl_down(o1, off, 64);
        }
        if (act && lane == 0) {
            out[(size_t)e * 2]     = o0 + b20;
            out[(size_t)e * 2 + 1] = o1 + b21;
        }
        __syncthreads();
    }
}

extern "C" void kernel_launch(void* const* d_in, const int* in_sizes, int n_in,
                              void* d_out, int out_size, void* d_ws, size_t ws_size,
                              hipStream_t stream)
{
    const float* x    = (const float*)d_in[0];
    const int*   ei   = (const int*)d_in[1];
    const float* ea   = (const float*)d_in[2];
    const float* W1l  = (const float*)d_in[3];
    const float* b1l  = (const float*)d_in[4];
    const float* W1r  = (const float*)d_in[5];
    const float* b1r  = (const float*)d_in[6];
    const float* W1e  = (const float*)d_in[7];
    const float* b1e  = (const float*)d_in[8];
    const float* att1 = (const float*)d_in[9];
    const float* bias1= (const float*)d_in[10];
    const float* W2l  = (const float*)d_in[11];
    const float* b2l  = (const float*)d_in[12];
    const float* W2r  = (const float*)d_in[13];
    const float* b2r  = (const float*)d_in[14];
    const float* W2e  = (const float*)d_in[15];
    const float* b2e  = (const float*)d_in[16];
    const float* att2 = (const float*)d_in[17];
    const float* bias2= (const float*)d_in[18];
    const float* Wm1  = (const float*)d_in[19];
    const float* bm1  = (const float*)d_in[20];
    const float* Wm2  = (const float*)d_in[21];
    const float* bm2  = (const float*)d_in[22];
    float* out = (float*)d_out;
    const int* srcp = ei;
    const int* dstp = ei + EE;

    float* ws = (float*)d_ws;
    size_t o_xl1    = 0;
    size_t o_xr1    = o_xl1 + (size_t)NN * C1;
    size_t o_h1     = o_xr1 + (size_t)NN * C1;       // ---- zeroed region starts here
    size_t o_amax1  = o_h1 + (size_t)NN * C1;
    size_t o_denom1 = o_amax1 + (size_t)NN * NH;
    size_t o_h2     = o_denom1 + (size_t)NN * NH;
    size_t o_amax2  = o_h2 + (size_t)NN * HIDD;
    size_t o_denom2 = o_amax2 + (size_t)NN;
    size_t o_zend   = o_denom2 + (size_t)NN;         // ---- zeroed region ends here
    size_t o_logits1= o_zend;
    size_t o_logits2= o_logits1 + (size_t)EE * NH;
    size_t o_xl2    = o_logits2 + (size_t)EE;
    size_t o_xr2    = o_xl2 + (size_t)NN * HIDD;

    hipMemsetAsync(ws + o_h1, 0, (o_zend - o_h1) * sizeof(float), stream);

    dim3 blk(256);
    k_lin1<<<(NN + 15) / 16, blk, 0, stream>>>(x, W1l, b1l, W1r, b1r, ws + o_xl1, ws + o_xr1);
    k_elog1<<<4096, blk, 0, stream>>>(srcp, dstp, ea, W1e, b1e, att1,
                                      ws + o_xl1, ws + o_xr1,
                                      ws + o_logits1, (unsigned*)(ws + o_amax1));
    k_exp1<<<2048, blk, 0, stream>>>(dstp, ws + o_logits1,
                                     (const unsigned*)(ws + o_amax1), ws + o_denom1);
    k_agg1<<<4096, blk, 0, stream>>>(srcp, dstp, ws + o_logits1, ws + o_denom1,
                                     ws + o_xl1, ws + o_h1);
    k_lin2<<<(NN + 15) / 16, blk, 0, stream>>>(ws + o_h1, bias1, W2l, b2l, W2r, b2r,
                                               ws + o_xl2, ws + o_xr2);
    k_elog2<<<4096, blk, 0, stream>>>(srcp, dstp, ea, W2e, b2e, att2,
                                      ws + o_xl2, ws + o_xr2,
                                      ws + o_logits2, (unsigned*)(ws + o_amax2));
    k_exp2<<<2048, blk, 0, stream>>>(dstp, ws + o_logits2,
                                     (const unsigned*)(ws + o_amax2), ws + o_denom2);
    k_agg2<<<4096, blk, 0, stream>>>(srcp, dstp, ws + o_logits2, ws + o_denom2,
                                     ws + o_xl2, ws + o_h2);
    k_fin2<<<2048, blk, 0, stream>>>(ws + o_h2, bias2);
    k_mlp<<<4096, blk, 0, stream>>>(srcp, dstp, ws + o_h2, ea, Wm1, bm1, Wm2, bm2, out);
}